// Round 10
// baseline (125.278 us; speedup 1.0000x reference)
//
#include <hip/hip_runtime.h>
#include <hip/hip_bf16.h>

// Problem constants (fixed by setup_inputs): coords (2, 4096, 3) float32, num_k = 30.
// Outputs: one flat FLOAT32 buffer, reference return order (established rounds 3/4).
// Input dtype runtime-sniffed (bf16 vs f32) as a hedge; rounds 4-9 confirm f32 path.
//
// R10 structure: each wave processes TWO rows (same batch, i and i+2048).
// Rationale (R9 post-mortem): kernel is dependency-latency-bound, not issue-bound
// (reported VALUBusy ~90% is gfx94x-formula 2x-inflated on SIMD-32). Twin rows give
// every serial chain (phase-1 insert, phase-2 DPP reductions, epilogue trans) an
// independent interleaving partner, and share phase-1 point loads + address math.
constexpr int B = 2;
constexpr int N = 4096;
constexpr int K = 30;
constexpr int HALF = N / 2;

constexpr size_t OFF_POS = 0;                                   // B*N*K*16
constexpr size_t OFF_AD  = OFF_POS + (size_t)B * N * K * 16;    // B*N*3
constexpr size_t OFF_O   = OFF_AD  + (size_t)B * N * 3;         // B*N*K*3
constexpr size_t OFF_GS  = OFF_O   + (size_t)B * N * K * 3;     // B*N*K*15
constexpr size_t OFF_DN  = OFF_GS  + (size_t)B * N * K * 15;    // B*N*K
constexpr size_t OFF_E   = OFF_DN  + (size_t)B * N * K;         // B*N*K

constexpr float BIGD = 1e30f;               // d identity (real d < 300)
constexpr unsigned int BIGJ = 0xFFFFFFFFu;  // j identity for u32 min

struct F3 { float x, y, z; };               // 12B -> global_load_dwordx3

template <bool ISBF16>
__device__ __forceinline__ float ldx(const void* __restrict__ X, int idx) {
  if constexpr (ISBF16) {
    return __bfloat162float(((const __hip_bfloat16*)X)[idx]);
  } else {
    return ((const float*)X)[idx];
  }
}

// Selection exactness lives HERE: np-exact f32 ops, no FMA. Phase-1 and refill
// must produce bit-identical d for the same (row, j).
__device__ __forceinline__ float dist_core(float px, float py, float pz,
                                           float xi, float yi, float zi) {
#pragma clang fp contract(off)
  const float dx = px - xi;
  const float dy = py - yi;
  const float dz = pz - zi;
  return sqrtf(((dx * dx + dy * dy) + dz * dz) + 1e-6f);
}

template <bool ISBF16>
__device__ __forceinline__ float distf(const void* __restrict__ Xb, int j,
                                       float xi, float yi, float zi) {
  float px, py, pz;
  if constexpr (ISBF16) {
    px = ldx<true>(Xb, j * 3 + 0);
    py = ldx<true>(Xb, j * 3 + 1);
    pz = ldx<true>(Xb, j * 3 + 2);
  } else {
    const F3 p = ((const F3*)Xb)[j];
    px = p.x; py = p.y; pz = p.z;
  }
  return dist_core(px, py, pz, xi, yi, zi);
}

// ---- DPP 64-lane min reductions, full-rate f32/u32 ops -------------------
template <int CTRL>
__device__ __forceinline__ float dpp_min_f32(float v) {
  const int mv = __builtin_amdgcn_update_dpp(__float_as_int(BIGD), __float_as_int(v),
                                             CTRL, 0xF, 0xF, false);
  return fminf(__int_as_float(mv), v);
}
template <int CTRL>
__device__ __forceinline__ unsigned int dpp_min_u32(unsigned int v) {
  const unsigned int mv = (unsigned int)__builtin_amdgcn_update_dpp(
      (int)BIGJ, (int)v, CTRL, 0xF, 0xF, false);
  return mv < v ? mv : v;
}
__device__ __forceinline__ float wave_min_f32_bcast(float v) {
  v = dpp_min_f32<0x111>(v);   // row_shr:1
  v = dpp_min_f32<0x112>(v);   // row_shr:2
  v = dpp_min_f32<0x114>(v);   // row_shr:4
  v = dpp_min_f32<0x118>(v);   // row_shr:8
  v = dpp_min_f32<0x142>(v);   // row_bcast:15
  v = dpp_min_f32<0x143>(v);   // row_bcast:31 -> lane 63 = global min
  return __int_as_float(__builtin_amdgcn_readlane(__float_as_int(v), 63));
}
__device__ __forceinline__ unsigned int wave_min_u32_bcast(unsigned int v) {
  v = dpp_min_u32<0x111>(v);
  v = dpp_min_u32<0x112>(v);
  v = dpp_min_u32<0x114>(v);
  v = dpp_min_u32<0x118>(v);
  v = dpp_min_u32<0x142>(v);
  v = dpp_min_u32<0x143>(v);
  return (unsigned int)__builtin_amdgcn_readlane((int)v, 63);
}

// Lex (d, j) argmin over per-lane heads; wave-uniform. Unique-dmin fast path:
// ffs + readlane (a tied in-column head already holds its smallest j). Rare
// multi-lane d-tie: exact u32 j-min reduction. == jax.lax.top_k stable order.
__device__ __forceinline__ void lex_argmin(float d0, int j0,
                                           float& dmin, unsigned int& jmin) {
  dmin = wave_min_f32_bcast(d0);
  const unsigned long long tie = __ballot(d0 == dmin);
  if (__popcll(tie) == 1) {
    const int wl = __ffsll(tie) - 1;
    jmin = (unsigned int)__builtin_amdgcn_readlane(j0, wl);
  } else {
    jmin = wave_min_u32_bcast((d0 == dmin) ? (unsigned int)j0 : BIGJ);
  }
}

// Cooperative refill of column w (wave-uniform w): recompute bit-identical
// distances, exclude consumed entries (mask lives in lane w), wave-min.
template <bool ISBF16>
__device__ __forceinline__ void refill(const void* __restrict__ Xb, int lane, int w,
                                       unsigned long long exm,
                                       float xi, float yi, float zi,
                                       float& d0, int& j0) {
  const unsigned int mlo = (unsigned int)__builtin_amdgcn_readlane((int)(unsigned int)(exm & 0xFFFFFFFFull), w);
  const unsigned int mhi = (unsigned int)__builtin_amdgcn_readlane((int)(unsigned int)(exm >> 32), w);
  const unsigned long long m = ((unsigned long long)mhi << 32) | mlo;
  const int j2 = (lane << 6) | w;
  const float d2 = distf<ISBF16>(Xb, j2, xi, yi, zi);
  const float dc = ((m >> lane) & 1ull) ? BIGD : d2;
  float dmin2; unsigned int jmin2;
  lex_argmin(dc, j2, dmin2, jmin2);
  if (lane == w) { d0 = dmin2; j0 = (int)jmin2; }
}

// range-reduce to |r| <= pi, then native sin/cos (safe hw domain)
__device__ __forceinline__ float red2pi(float x) {
  return x - 6.28318530718f * rintf(x * 0.15915494309f);
}

// normalize with eps=1e-12 (FMA contraction allowed: 2% output threshold)
__device__ __forceinline__ void norm3(float& x, float& y, float& z) {
  float n = sqrtf((x * x + y * y) + z * z);
  n = fmaxf(n, 1e-12f);
  x /= n; y /= n; z /= n;
}

__device__ __forceinline__ void cross3(float ax, float ay, float az,
                                       float bx, float by, float bz,
                                       float& cx, float& cy, float& cz) {
  cx = ay * bz - az * by;
  cy = az * bx - ax * bz;
  cz = ax * by - ay * bx;
}

// Per-row epilogue: AD/O3 frame + all feature writes for one row.
template <bool ISBF16>
__device__ __forceinline__ void epilogue(const void* __restrict__ Xb,
                                         float* __restrict__ out,
                                         int b, int i, int lane,
                                         int sjv, float sdv,
                                         float xi, float yi, float zi) {
  float ad0 = 0.f, ad1 = 0.f, ad2 = 0.f;
  float o00 = 0.f, o01 = 0.f, o02 = 0.f;
  float o10 = 0.f, o11 = 0.f, o12 = 0.f;
  float o20 = 0.f, o21 = 0.f, o22 = 0.f;
  if (i >= 1 && i <= N - 3) {
    const float ax = ldx<ISBF16>(Xb, (i - 1) * 3 + 0), ay = ldx<ISBF16>(Xb, (i - 1) * 3 + 1), az = ldx<ISBF16>(Xb, (i - 1) * 3 + 2);
    const float cx = ldx<ISBF16>(Xb, (i + 1) * 3 + 0), cy = ldx<ISBF16>(Xb, (i + 1) * 3 + 1), cz = ldx<ISBF16>(Xb, (i + 1) * 3 + 2);
    const float ex = ldx<ISBF16>(Xb, (i + 2) * 3 + 0), ey = ldx<ISBF16>(Xb, (i + 2) * 3 + 1), ez = ldx<ISBF16>(Xb, (i + 2) * 3 + 2);
    float u2x = xi - ax, u2y = yi - ay, u2z = zi - az; norm3(u2x, u2y, u2z);  // U[i-1]
    float u1x = cx - xi, u1y = cy - yi, u1z = cz - zi; norm3(u1x, u1y, u1z);  // U[i]
    float u0x = ex - cx, u0y = ey - cy, u0z = ez - cz; norm3(u0x, u0y, u0z);  // U[i+1]
    float n2x, n2y, n2z; cross3(u2x, u2y, u2z, u1x, u1y, u1z, n2x, n2y, n2z); norm3(n2x, n2y, n2z);
    float n1x, n1y, n1z; cross3(u1x, u1y, u1z, u0x, u0y, u0z, n1x, n1y, n1z); norm3(n1x, n1y, n1z);
    const float dotu = (u1x * u0x + u1y * u0y) + u1z * u0z;
    const float cosA = fminf(fmaxf(-dotu, -1.0f + 1e-6f), 1.0f - 1e-6f);
    const float A = acosf(cosA);                    // in [0, pi]
    const float dotn = (n2x * n1x + n2y * n1y) + n2z * n1z;
    const float cosD = fminf(fmaxf(dotn, -1.0f + 1e-6f), 1.0f - 1e-6f);
    const float du2n1 = (u2x * n1x + u2y * n1y) + u2z * n1z;
    const float sg = (du2n1 > 0.f) ? 1.f : ((du2n1 < 0.f) ? -1.f : 0.f);
    const float Dang = sg * acosf(cosD);            // in [-pi, pi]
    const float sA = __sinf(A),    cA = __cosf(A);
    const float sD = __sinf(Dang), cD = __cosf(Dang);
    ad0 = cA; ad1 = sA * cD; ad2 = sA * sD;
    float o1x = u2x - u1x, o1y = u2y - u1y, o1z = u2z - u1z; norm3(o1x, o1y, o1z);
    o00 = o1x; o01 = o1y; o02 = o1z;
    o10 = n2x; o11 = n2y; o12 = n2z;
    cross3(o1x, o1y, o1z, n2x, n2y, n2z, o20, o21, o22);
  }

  const int row = b * N + i;

  // pos_emb: 480 contiguous values; p = idx & 15 loop-invariant per lane.
  {
    const size_t base = OFF_POS + (size_t)row * (K * 16);
    const int p = lane & 15;
    const float fr = __expf((float)((p & 7) * 2) * -0.57564627f);
    const bool is_cos = (p < 8);
#pragma unroll
    for (int it = 0; it < 8; ++it) {
      const int idx = it * 64 + lane;
      const int k = (idx >> 4) < K ? (idx >> 4) : (K - 1);
      const int jk = __shfl(sjv, k, 64);
      const float df = (float)(jk - i);
      const float r = red2pi(df * fr);
      const float v = is_cos ? __cosf(r) : __sinf(r);
      if (idx < K * 16) out[base + idx] = v;
    }
  }

  // gs_d: 450 contiguous values.
  {
    const size_t base = OFF_GS + (size_t)row * (K * 15);
#pragma unroll
    for (int it = 0; it < 8; ++it) {
      const int idx = it * 64 + lane;
      const int kq = idx / 15;
      const int k = kq < K ? kq : (K - 1);
      const int m = idx - kq * 15;
      const float d = __shfl(sdv, k, 64);
      const float mu = (float)(m * (20.0 / 14.0));
      const float q = (d - mu) / 1.3333334f;
      const float v = __expf(-(q * q));
      if (idx < K * 15) out[base + idx] = v;
    }
  }

  // E_idx, D_neighbors, O_features on lanes < K; AD on lanes 30..32.
  if (lane < K) {
    const size_t rowk = (size_t)row * K + lane;
    const int j = sjv;
    out[OFF_E  + rowk] = (float)j;
    out[OFF_DN + rowk] = sdv;

    float px, py, pz;
    if constexpr (ISBF16) {
      px = ldx<true>(Xb, j * 3 + 0);
      py = ldx<true>(Xb, j * 3 + 1);
      pz = ldx<true>(Xb, j * 3 + 2);
    } else {
      const F3 p = ((const F3*)Xb)[j];
      px = p.x; py = p.y; pz = p.z;
    }
    const float gx = px - xi, gy = py - yi, gz = pz - zi;
    const float v0 = (o00 * gx + o01 * gy) + o02 * gz;
    const float v1 = (o10 * gx + o11 * gy) + o12 * gz;
    const float v2 = (o20 * gx + o21 * gy) + o22 * gz;
    const float nn = fmaxf(sqrtf((v0 * v0 + v1 * v1) + v2 * v2), 1e-12f);
    out[OFF_O + rowk * 3 + 0] = v0 / nn;
    out[OFF_O + rowk * 3 + 1] = v1 / nn;
    out[OFF_O + rowk * 3 + 2] = v2 / nn;
  } else if (lane < K + 3) {
    const int c = lane - K;
    const float v = (c == 0) ? ad0 : (c == 1) ? ad1 : ad2;
    out[OFF_AD + (size_t)row * 3 + c] = v;
  }
}

template <bool ISBF16>
__device__ __forceinline__ void body(const void* __restrict__ Xb,
                                     float* __restrict__ out,
                                     int b, int iA, int iB, int lane) {
  const float xiA = ldx<ISBF16>(Xb, iA * 3 + 0);
  const float yiA = ldx<ISBF16>(Xb, iA * 3 + 1);
  const float ziA = ldx<ISBF16>(Xb, iA * 3 + 2);
  const float xiB = ldx<ISBF16>(Xb, iB * 3 + 0);
  const float yiB = ldx<ISBF16>(Xb, iB * 3 + 1);
  const float ziB = ldx<ISBF16>(Xb, iB * 3 + 2);

  // ---- Phase 1 (dual): one shared point load feeds both rows' distance
  // chains; two independent sorted top-2 caches. Strict < on d is j-stable
  // (j ascends within a column).
  float d0A = BIGD, d1A = BIGD, d0B = BIGD, d1B = BIGD;
  int   j0A = 0x7FFFFFFF, j1A = 0x7FFFFFFF, j0B = 0x7FFFFFFF, j1B = 0x7FFFFFFF;
#pragma unroll 4
  for (int t = 0; t < 64; ++t) {
    const int j = t * 64 + lane;
    float px, py, pz;
    if constexpr (ISBF16) {
      px = ldx<true>(Xb, j * 3 + 0);
      py = ldx<true>(Xb, j * 3 + 1);
      pz = ldx<true>(Xb, j * 3 + 2);
    } else {
      const F3 p = ((const F3*)Xb)[j];   // shared dwordx3
      px = p.x; py = p.y; pz = p.z;
    }
    const float dA = dist_core(px, py, pz, xiA, yiA, ziA);
    const float dB = dist_core(px, py, pz, xiB, yiB, ziB);
    {
      const bool lt1 = dA < d1A;
      const float td = lt1 ? dA : d1A;
      const int   tj = lt1 ? j : j1A;
      const bool lt0 = td < d0A;
      d1A = lt0 ? d0A : td;  j1A = lt0 ? j0A : tj;
      d0A = lt0 ? td : d0A;  j0A = lt0 ? tj : j0A;
    }
    {
      const bool lt1 = dB < d1B;
      const float td = lt1 ? dB : d1B;
      const int   tj = lt1 ? j : j1B;
      const bool lt0 = td < d0B;
      d1B = lt0 ? d0B : td;  j1B = lt0 ? j0B : tj;
      d0B = lt0 ? td : d0B;  j0B = lt0 ? tj : j0B;
    }
  }

  // ---- Phase 2 (dual): 30 pops; the two DPP reduction chains are
  // independent and written adjacently so the scheduler interleaves them.
  unsigned long long exmA = 0, exmB = 0;
  int   sjvA = 0, sjvB = 0;
  float sdvA = 0.0f, sdvB = 0.0f;
  for (int k = 0; k < K; ++k) {
    const float dminA = wave_min_f32_bcast(d0A);   // chain A
    const float dminB = wave_min_f32_bcast(d0B);   // chain B (interleaves)
    const unsigned long long tieA = __ballot(d0A == dminA);
    const unsigned long long tieB = __ballot(d0B == dminB);
    unsigned int jminA, jminB;
    if (__popcll(tieA) == 1) {
      jminA = (unsigned int)__builtin_amdgcn_readlane(j0A, __ffsll(tieA) - 1);
    } else {
      jminA = wave_min_u32_bcast((d0A == dminA) ? (unsigned int)j0A : BIGJ);
    }
    if (__popcll(tieB) == 1) {
      jminB = (unsigned int)__builtin_amdgcn_readlane(j0B, __ffsll(tieB) - 1);
    } else {
      jminB = wave_min_u32_bcast((d0B == dminB) ? (unsigned int)j0B : BIGJ);
    }
    if (lane == k) { sjvA = (int)jminA; sdvA = dminA; sjvB = (int)jminB; sdvB = dminB; }

    const int wA = (int)(jminA & 63u), twA = (int)(jminA >> 6);
    const int wB = (int)(jminB & 63u), twB = (int)(jminB >> 6);
    if (lane == wA) { exmA |= (1ull << twA); d0A = d1A; j0A = j1A; d1A = BIGD; j1A = 0x7FFFFFFF; }
    if (lane == wB) { exmB |= (1ull << twB); d0B = d1B; j0B = j1B; d1B = BIGD; j1B = 0x7FFFFFFF; }

    const unsigned long long eA = __ballot(d0A == BIGD);
    const unsigned long long eB = __ballot(d0B == BIGD);
    if (eA | eB) {               // rare (~0.65/row): cooperative column refill
      if (eA) refill<ISBF16>(Xb, lane, wA, exmA, xiA, yiA, ziA, d0A, j0A);
      if (eB) refill<ISBF16>(Xb, lane, wB, exmB, xiB, yiB, ziB, d0B, j0B);
    }
  }

  // ---- Epilogues (sequential per row: keeps only one AD/O3 frame live). ----
  epilogue<ISBF16>(Xb, out, b, iA, lane, sjvA, sdvA, xiA, yiA, ziA);
  epilogue<ISBF16>(Xb, out, b, iB, lane, sjvB, sdvB, xiB, yiB, ziB);
}

__global__ __launch_bounds__(256)
void protein_feat_kernel(const void* __restrict__ X,
                         float* __restrict__ out) {
  const int lane = threadIdx.x & 63;
  const int wv   = threadIdx.x >> 6;              // wave id within WG
  const int l    = blockIdx.x * 4 + wv;           // 0..B*HALF-1
  const int b    = l >> 11;                       // l / HALF
  const int i0   = l & (HALF - 1);
  const int iA   = i0;
  const int iB   = i0 + HALF;

  // ---- Input-dtype sniff (hedge): even-indexed uint16s are sane bf16 coords
  // iff the buffer is truly bf16; for float32 they are mantissa noise.
  const unsigned short h = ((const unsigned short*)X)[2 * lane];
  const int e = (h >> 7) & 0xFF;
  const bool sane = ((h & 0x7FFF) == 0) || (e >= 115 && e <= 134);
  const unsigned long long bal = __ballot(sane);
  const bool isbf16 = __popcll(bal) >= 40;

  if (isbf16) {
    const void* Xb = (const void*)((const __hip_bfloat16*)X + (size_t)b * N * 3);
    body<true>(Xb, out, b, iA, iB, lane);
  } else {
    const void* Xb = (const void*)((const float*)X + (size_t)b * N * 3);
    body<false>(Xb, out, b, iA, iB, lane);
  }
}

extern "C" void kernel_launch(void* const* d_in, const int* in_sizes, int n_in,
                              void* d_out, int out_size, void* d_ws, size_t ws_size,
                              hipStream_t stream) {
  const void* X = d_in[0];
  float* out = (float*)d_out;
  (void)in_sizes; (void)n_in; (void)d_ws; (void)ws_size; (void)out_size;
  protein_feat_kernel<<<dim3(B * HALF / 4), dim3(256), 0, stream>>>(X, out);
}